// Round 5
// baseline (2317.361 us; speedup 1.0000x reference)
//
#include <hip/hip_runtime.h>
#include <stdint.h>

typedef __attribute__((ext_vector_type(8))) short bf16x8;
typedef __attribute__((ext_vector_type(4))) float f32x4;

#define DEV __device__ __forceinline__

DEV unsigned short f2bf(float f) {
    unsigned b = __float_as_uint(f);
    unsigned r = (b + 0x7fffu + ((b >> 16) & 1u)) >> 16;   // RNE
    return (unsigned short)r;
}
DEV unsigned pack2(float a, float b) {
    return (unsigned)f2bf(a) | ((unsigned)f2bf(b) << 16);
}
DEV bf16x8 pack8(float4 f0, float4 f1) {
    bf16x8 r;
    r[0] = (short)f2bf(f0.x); r[1] = (short)f2bf(f0.y);
    r[2] = (short)f2bf(f0.z); r[3] = (short)f2bf(f0.w);
    r[4] = (short)f2bf(f1.x); r[5] = (short)f2bf(f1.y);
    r[6] = (short)f2bf(f1.z); r[7] = (short)f2bf(f1.w);
    return r;
}
DEV float sigm(float x) { return 1.f / (1.f + __expf(-x)); }
DEV float tanh_f(float x) {
    float t = __expf(-2.f * fabsf(x));
    float r = (1.f - t) / (1.f + t);
    return copysignf(r, x);
}

// ws layout (bytes); base footprint identical to the proven round-3 layout.
// [0, 32768):      u64 ring2[2][2048]  layer-2 recurrent ring; REUSED as
//                  f32 lse[4096] after scan3 completes (ring2 dead by then)
// [32768, 65536):  u64 lacc[4096]      packed (m:lo32, s:hi32) online-LSE acc
#define OFF_HB0   65536                       // 4 MB u64 Hb0[256][2048]
#define OFF_HB1   (65536 + 4194304)           // 4 MB u64 Hb1[256][2048]
#define OFF_XEA   (65536 + 8388608)           // 2 MB bf16 XeA[256][4096]
#define OFF_HS    (OFF_XEA + 2097152)         // 2 MB bf16 hs[4096][256]
#define OFF_WB    (OFF_HS + 2097152)          // optional 16.4 MB bf16 Wb[32000][256]
#define WB_BYTES  (32000u * 256u * 2u)

// ---------------------------------------------------------------------------
// Embedding gather + fp32->bf16 in per-timestep A-frag order
// ---------------------------------------------------------------------------
__global__ __launch_bounds__(256) void k_embed(const int* __restrict__ x,
                                               const float* __restrict__ emb,
                                               unsigned short* __restrict__ XeA)
{
    int row = blockIdx.x * 8 + (threadIdx.x >> 5);
    int i = threadIdx.x & 31;
    int tok = x[row];
    int b = row >> 8, t = row & 255;
    uint4 v = make_uint4(0, 0, 0, 0);
    if (i < 25) {
        const float* p = emb + (size_t)tok * 200 + i * 8;
        float4 f0 = *(const float4*)p;
        float4 f1 = *(const float4*)(p + 4);
        v.x = pack2(f0.x, f0.y); v.y = pack2(f0.z, f0.w);
        v.z = pack2(f1.x, f1.y); v.w = pack2(f1.z, f1.w);
    }
    int kt = i >> 2, qq = i & 3;
    *(uint4*)(XeA + (size_t)t * 4096 + (size_t)((kt * 64 + qq * 16 + b) * 8)) = v;
}

// ---------------------------------------------------------------------------
// One-shot fcW fp32 -> bf16 pre-conversion (only if workspace allows)
// ---------------------------------------------------------------------------
__global__ __launch_bounds__(256) void k_wcvt(const float* __restrict__ W,
                                              unsigned short* __restrict__ Wb)
{
    size_t i = ((size_t)blockIdx.x * 256 + threadIdx.x) * 8;
    float4 f0 = *(const float4*)(W + i);
    float4 f1 = *(const float4*)(W + i + 4);
    uint4 v;
    v.x = pack2(f0.x, f0.y); v.y = pack2(f0.z, f0.w);
    v.z = pack2(f1.x, f1.y); v.w = pack2(f1.z, f1.w);
    *(uint4*)(Wb + i) = v;
}

// ---------------------------------------------------------------------------
// Device-scope online-logsumexp merge into packed u64 {s:hi32, m:lo32}.
// memset-0 state (m=0,s=0) is the identity (s==0 test).
// ---------------------------------------------------------------------------
DEV void lse_cas_merge(unsigned long long* p, float m, float s)
{
    unsigned long long old = __hip_atomic_load(p, __ATOMIC_RELAXED, __HIP_MEMORY_SCOPE_AGENT);
    while (true) {
        unsigned long long assumed = old;
        float mo = __uint_as_float((unsigned)(assumed & 0xffffffffu));
        float so = __uint_as_float((unsigned)(assumed >> 32));
        float nm, ns;
        if (so == 0.f) { nm = m; ns = s; }
        else {
            nm = fmaxf(mo, m);
            ns = so * __expf(mo - nm) + s * __expf(m - nm);
        }
        unsigned long long nv =
            ((unsigned long long)__float_as_uint(ns) << 32) | (unsigned long long)__float_as_uint(nm);
        old = atomicCAS(p, assumed, nv);
        if (old == assumed) break;
    }
}

// ---------------------------------------------------------------------------
// FC GEMM, two passes over identical deterministic MFMA compute:
//   MODE 0: no logit stores; per-row (max, sum-exp) over this block's 128
//           cols -> CAS-merge into lacc[row]. 8 MB -> 32 KB traffic.
//   MODE 1: recompute acc, write out = acc + bias - lse[row] (final
//           log-softmax) directly. Logits hit HBM exactly once.
// WB=1 uses pre-converted bf16 weights, WB=0 converts fp32 in staging.
// ---------------------------------------------------------------------------
template <int WB, int MODE>
__global__ __launch_bounds__(256) void k_fc(const unsigned short* __restrict__ X,
                                            const float* __restrict__ W,
                                            const unsigned short* __restrict__ Wb,
                                            const float* __restrict__ bias,
                                            unsigned long long* __restrict__ lacc,
                                            const float* __restrict__ lse,
                                            float* __restrict__ outf)
{
    __shared__ __align__(16) unsigned short Al[128 * 72];
    __shared__ __align__(16) unsigned short Bl[128 * 72];
    __shared__ float red[2][64][2][2];   // [wm][row64][wn][{m,s}] (MODE 0)
    const int tid = threadIdx.x, lane = tid & 63, wave = tid >> 6;
    const int wm = wave >> 1, wn = wave & 1;
    const int bm = blockIdx.y, bn = blockIdx.x;
    const int l15 = lane & 15, q = lane >> 4;

    f32x4 acc[4][4];
#pragma unroll
    for (int a = 0; a < 4; a++)
#pragma unroll
        for (int b = 0; b < 4; b++) acc[a][b] = f32x4{0.f, 0.f, 0.f, 0.f};

    for (int kb = 0; kb < 256; kb += 64) {
        __syncthreads();
#pragma unroll
        for (int it = 0; it < 4; ++it) {
            int p = tid + it * 256;
            int row = p >> 3, c8 = p & 7;
            int col = kb + c8 * 8;
            uint4 av = *(const uint4*)(X + (size_t)(bm * 128 + row) * 256 + col);
            *(uint4*)(Al + row * 72 + c8 * 8) = av;
            uint4 bv;
            if (WB) {
                bv = *(const uint4*)(Wb + (size_t)(bn * 128 + row) * 256 + col);
            } else {
                const float* wp = W + (size_t)(bn * 128 + row) * 256 + col;
                float4 f0 = *(const float4*)wp;
                float4 f1 = *(const float4*)(wp + 4);
                bv.x = pack2(f0.x, f0.y); bv.y = pack2(f0.z, f0.w);
                bv.z = pack2(f1.x, f1.y); bv.w = pack2(f1.z, f1.w);
            }
            *(uint4*)(Bl + row * 72 + c8 * 8) = bv;
        }
        __syncthreads();
#pragma unroll
        for (int kt = 0; kt < 2; ++kt) {
            bf16x8 a[4], b[4];
#pragma unroll
            for (int mt = 0; mt < 4; ++mt)
                a[mt] = *(const bf16x8*)(Al + (wm * 64 + mt * 16 + l15) * 72 + kt * 32 + q * 8);
#pragma unroll
            for (int nt = 0; nt < 4; ++nt)
                b[nt] = *(const bf16x8*)(Bl + (wn * 64 + nt * 16 + l15) * 72 + kt * 32 + q * 8);
#pragma unroll
            for (int mt = 0; mt < 4; ++mt)
#pragma unroll
                for (int nt = 0; nt < 4; ++nt)
                    acc[mt][nt] = __builtin_amdgcn_mfma_f32_16x16x32_bf16(a[mt], b[nt], acc[mt][nt], 0, 0, 0);
        }
    }

    if (MODE == 0) {
        float bvv[4];
#pragma unroll
        for (int nt = 0; nt < 4; ++nt) bvv[nt] = bias[bn * 128 + wn * 64 + nt * 16 + l15];
#pragma unroll
        for (int mt = 0; mt < 4; ++mt) {
#pragma unroll
            for (int r = 0; r < 4; ++r) {
                float v0 = acc[mt][0][r] + bvv[0];
                float v1 = acc[mt][1][r] + bvv[1];
                float v2 = acc[mt][2][r] + bvv[2];
                float v3 = acc[mt][3][r] + bvv[3];
                float m = fmaxf(fmaxf(v0, v1), fmaxf(v2, v3));
#pragma unroll
                for (int off = 1; off <= 8; off <<= 1) m = fmaxf(m, __shfl_xor(m, off));
                float s = __expf(v0 - m) + __expf(v1 - m) + __expf(v2 - m) + __expf(v3 - m);
#pragma unroll
                for (int off = 1; off <= 8; off <<= 1) s += __shfl_xor(s, off);
                if (l15 == 0) {
                    int rl = mt * 16 + q * 4 + r;
                    red[wm][rl][wn][0] = m;
                    red[wm][rl][wn][1] = s;
                }
            }
        }
        __syncthreads();
        if (tid < 128) {
            int wmx = tid >> 6, rl = tid & 63;
            float m0 = red[wmx][rl][0][0], s0 = red[wmx][rl][0][1];
            float m1 = red[wmx][rl][1][0], s1 = red[wmx][rl][1][1];
            float nm = fmaxf(m0, m1);
            float ns = s0 * __expf(m0 - nm) + s1 * __expf(m1 - nm);
            lse_cas_merge(lacc + bm * 128 + tid, nm, ns);
        }
    } else {
        float lsv[16];
#pragma unroll
        for (int mt = 0; mt < 4; ++mt)
#pragma unroll
            for (int r = 0; r < 4; ++r)
                lsv[mt * 4 + r] = lse[bm * 128 + wm * 64 + mt * 16 + q * 4 + r];
#pragma unroll
        for (int nt = 0; nt < 4; ++nt) {
            int gn = bn * 128 + wn * 64 + nt * 16 + l15;
            float bv = bias[gn];
#pragma unroll
            for (int mt = 0; mt < 4; ++mt) {
#pragma unroll
                for (int r = 0; r < 4; ++r) {
                    int gm = bm * 128 + wm * 64 + mt * 16 + q * 4 + r;
                    outf[(size_t)gm * 32000 + gn] = acc[mt][nt][r] + bv - lsv[mt * 4 + r];
                }
            }
        }
    }
}

// ---------------------------------------------------------------------------
// lse[i] = m + log(s) from packed accumulator
// ---------------------------------------------------------------------------
__global__ __launch_bounds__(256) void k_lsefin(const unsigned long long* __restrict__ lacc,
                                                float* __restrict__ lse)
{
    int i = blockIdx.x * 256 + threadIdx.x;
    unsigned long long v = lacc[i];
    float m = __uint_as_float((unsigned)(v & 0xffffffffu));
    float s = __uint_as_float((unsigned)(v >> 32));
    lse[i] = m + __logf(s);
}

// ---------------------------------------------------------------------------
// Fused 3-layer LSTM scan with cross-layer pipelining (frozen from round 3).
// ---------------------------------------------------------------------------
__global__ __launch_bounds__(256) void k_scan3(
    const float* __restrict__ Wi0, const float* __restrict__ Wh0, const float* __restrict__ b0,
    const float* __restrict__ Wi1, const float* __restrict__ Wh1, const float* __restrict__ b1,
    const float* __restrict__ Wi2, const float* __restrict__ Wh2, const float* __restrict__ b2,
    const unsigned short* __restrict__ XeA,
    unsigned short* __restrict__ hseq,
    unsigned long long* __restrict__ Hb0,
    unsigned long long* __restrict__ Hb1,
    unsigned long long* __restrict__ ring2)
{
    __shared__ __align__(16) unsigned short hX[4096];
    __shared__ __align__(16) unsigned short hH[4096];
    __shared__ float gbuf[64 * 17];
    const int tid = threadIdx.x, lane = tid & 63, wave = tid >> 6;
    const int L = blockIdx.x >> 4, s = blockIdx.x & 15;
    const int l15 = lane & 15, q = lane >> 4;
    const int grow = wave * 256 + s * 16 + l15;

    const float* Wi = (L == 0) ? Wi0 : ((L == 1) ? Wi1 : Wi2);
    const float* Wh = (L == 0) ? Wh0 : ((L == 1) ? Wh1 : Wh2);
    const float* bb = (L == 0) ? b0 : ((L == 1) ? b1 : b2);
    const int KX = (L == 0) ? 200 : 256;

    bf16x8 WiR[8], WhR[8];
#pragma unroll
    for (int kt = 0; kt < 8; ++kt) {
        int k0 = kt * 32 + q * 8;
        {
            const float* p = Wh + (size_t)grow * 256 + k0;
            WhR[kt] = pack8(*(const float4*)p, *(const float4*)(p + 4));
        }
        if (k0 < KX) {
            const float* p = Wi + (size_t)grow * KX + k0;
            WiR[kt] = pack8(*(const float4*)p, *(const float4*)(p + 4));
        } else {
            WiR[kt] = bf16x8{0, 0, 0, 0, 0, 0, 0, 0};
        }
    }
    const float bv = bb[grow];

    const int eb = tid >> 4, eu = tid & 15;
    const bool pub = (eu & 1) == 0;
    int slot;
    {
        int ug = s * 16 + eu;
        int kt = ug >> 5, qq = (ug >> 3) & 3, j = ug & 7;
        slot = ((kt * 64 + qq * 16 + eb) * 8 + j) >> 1;
    }
    float c = 0.f;
    unsigned* hX32 = (unsigned*)hX;
    unsigned* hH32 = (unsigned*)hH;

    const unsigned long long* xbase = (L == 1) ? Hb0 : Hb1;
    unsigned long long* obase = (L == 0) ? Hb0 : Hb1;
    const unsigned long long* rbase = (L == 0) ? Hb0 : Hb1;

    for (int t = 0; t < 256; ++t) {
        if (L == 0) {
            const unsigned* srcx = (const unsigned*)(XeA + (size_t)t * 4096);
            *(uint4*)(hX32 + tid * 8)     = *(const uint4*)(srcx + tid * 8);
            *(uint4*)(hX32 + tid * 8 + 4) = *(const uint4*)(srcx + tid * 8 + 4);
        }
        {
            unsigned long long vx[8], vh[8];
            unsigned pendx = (L > 0) ? 0xffu : 0u;
            unsigned pendh = (t > 0) ? 0xffu : 0u;
            const unsigned long long* sx = xbase + (size_t)t * 2048 + tid;
            const unsigned long long* sh =
                (L == 2) ? (ring2 + ((t - 1) & 1) * 2048 + tid)
                         : (rbase + (size_t)((t > 0) ? (t - 1) : 0) * 2048 + tid);
            const unsigned ex = (unsigned)(t + 1), eh = (unsigned)t;
            while (pendx | pendh) {
#pragma unroll
                for (int i = 0; i < 8; ++i)
                    if (pendx & (1u << i))
                        vx[i] = __hip_atomic_load(sx + i * 256, __ATOMIC_RELAXED,
                                                  __HIP_MEMORY_SCOPE_AGENT);
#pragma unroll
                for (int i = 0; i < 8; ++i)
                    if (pendh & (1u << i))
                        vh[i] = __hip_atomic_load(sh + i * 256, __ATOMIC_RELAXED,
                                                  __HIP_MEMORY_SCOPE_AGENT);
#pragma unroll
                for (int i = 0; i < 8; ++i) {
                    if ((pendx & (1u << i)) && (unsigned)(vx[i] >> 32) == ex) pendx &= ~(1u << i);
                    if ((pendh & (1u << i)) && (unsigned)(vh[i] >> 32) == eh) pendh &= ~(1u << i);
                }
                if (pendx | pendh) __builtin_amdgcn_s_sleep(1);
            }
            if (L > 0) {
#pragma unroll
                for (int i = 0; i < 8; ++i) hX32[tid + i * 256] = (unsigned)vx[i];
            }
            if (t > 0) {
#pragma unroll
                for (int i = 0; i < 8; ++i) hH32[tid + i * 256] = (unsigned)vh[i];
            } else {
#pragma unroll
                for (int i = 0; i < 8; ++i) hH32[tid + i * 256] = 0u;
            }
        }
        __syncthreads();

        f32x4 acc0 = {bv, bv, bv, bv};
        f32x4 acc1 = {0.f, 0.f, 0.f, 0.f};
#pragma unroll
        for (int kt = 0; kt < 8; ++kt) {
            bf16x8 ax = *(const bf16x8*)(hX + (kt * 64 + lane) * 8);
            acc0 = __builtin_amdgcn_mfma_f32_16x16x32_bf16(ax, WiR[kt], acc0, 0, 0, 0);
            bf16x8 ah = *(const bf16x8*)(hH + (kt * 64 + lane) * 8);
            acc1 = __builtin_amdgcn_mfma_f32_16x16x32_bf16(ah, WhR[kt], acc1, 0, 0, 0);
        }
        {
            int rowb = wave * 16 + l15;
#pragma unroll
            for (int r = 0; r < 4; ++r) gbuf[rowb * 17 + q * 4 + r] = acc0[r] + acc1[r];
        }
        __syncthreads();

        float gi = gbuf[(0 * 16 + eu) * 17 + eb];
        float gf = gbuf[(1 * 16 + eu) * 17 + eb];
        float gg = gbuf[(2 * 16 + eu) * 17 + eb];
        float go = gbuf[(3 * 16 + eu) * 17 + eb];
        float i_ = sigm(gi), f_ = sigm(gf), g_ = tanh_f(gg), o_ = sigm(go);
        c = f_ * c + i_ * g_;
        float h = o_ * tanh_f(c);
        float hn = __shfl_xor(h, 1);
        if (pub) {
            unsigned pk = pack2(h, hn);
            unsigned long long val =
                ((unsigned long long)(unsigned)(t + 1) << 32) | (unsigned long long)pk;
            if (L == 2) {
                __hip_atomic_store(ring2 + (t & 1) * 2048 + slot, val, __ATOMIC_RELAXED,
                                   __HIP_MEMORY_SCOPE_AGENT);
                *(unsigned*)(hseq + (size_t)(eb * 256 + t) * 256 + s * 16 + eu) = pk;
            } else {
                __hip_atomic_store(obase + (size_t)t * 2048 + slot, val, __ATOMIC_RELAXED,
                                   __HIP_MEMORY_SCOPE_AGENT);
            }
        }
    }
}

// ---------------------------------------------------------------------------
extern "C" void kernel_launch(void* const* d_in, const int* in_sizes, int n_in,
                              void* d_out, int out_size, void* d_ws, size_t ws_size,
                              hipStream_t stream)
{
    const int* x = (const int*)d_in[0];
    const float* emb = (const float*)d_in[1];
    const float* Wi0 = (const float*)d_in[2];
    const float* Wh0 = (const float*)d_in[3];
    const float* b0  = (const float*)d_in[4];
    const float* Wi1 = (const float*)d_in[5];
    const float* Wh1 = (const float*)d_in[6];
    const float* b1  = (const float*)d_in[7];
    const float* Wi2 = (const float*)d_in[8];
    const float* Wh2 = (const float*)d_in[9];
    const float* b2  = (const float*)d_in[10];
    const float* fcW = (const float*)d_in[11];
    const float* fcb = (const float*)d_in[12];
    float* out = (float*)d_out;

    uint8_t* w = (uint8_t*)d_ws;
    unsigned long long* ring2 = (unsigned long long*)w;
    unsigned long long* lacc  = (unsigned long long*)(w + 32768);
    float* lse = (float*)w;   // reuses ring2 bytes; ring2 dead after k_scan3
    unsigned long long* Hb0 = (unsigned long long*)(w + OFF_HB0);
    unsigned long long* Hb1 = (unsigned long long*)(w + OFF_HB1);
    unsigned short* XeA = (unsigned short*)(w + OFF_XEA);
    unsigned short* hs  = (unsigned short*)(w + OFF_HS);
    unsigned short* Wb  = (unsigned short*)(w + OFF_WB);
    const bool wb_ok = ws_size >= (size_t)OFF_WB + (size_t)WB_BYTES;

    hipMemsetAsync(w, 0, OFF_XEA, stream);   // ring2 + lacc + Hb0/Hb1 tags

    if (wb_ok) k_wcvt<<<4000, 256, 0, stream>>>(fcW, Wb);

    k_embed<<<512, 256, 0, stream>>>(x, emb, XeA);

    k_scan3<<<48, 256, 0, stream>>>(Wi0, Wh0, b0, Wi1, Wh1, b1, Wi2, Wh2, b2,
                                    XeA, hs, Hb0, Hb1, ring2);

    if (wb_ok) {
        k_fc<1, 0><<<dim3(250, 32), 256, 0, stream>>>(hs, nullptr, Wb, fcb, lacc, nullptr, nullptr);
        k_lsefin<<<16, 256, 0, stream>>>(lacc, lse);
        k_fc<1, 1><<<dim3(250, 32), 256, 0, stream>>>(hs, nullptr, Wb, fcb, nullptr, lse, out);
    } else {
        k_fc<0, 0><<<dim3(250, 32), 256, 0, stream>>>(hs, fcW, nullptr, fcb, lacc, nullptr, nullptr);
        k_lsefin<<<16, 256, 0, stream>>>(lacc, lse);
        k_fc<0, 1><<<dim3(250, 32), 256, 0, stream>>>(hs, fcW, nullptr, fcb, nullptr, lse, out);
    }
}

// Round 6
// 1447.681 us; speedup vs baseline: 1.6007x; 1.6007x over previous
//
#include <hip/hip_runtime.h>
#include <stdint.h>

typedef __attribute__((ext_vector_type(8))) short bf16x8;
typedef __attribute__((ext_vector_type(4))) float f32x4;

#define DEV __device__ __forceinline__

DEV unsigned short f2bf(float f) {
    unsigned b = __float_as_uint(f);
    unsigned r = (b + 0x7fffu + ((b >> 16) & 1u)) >> 16;   // RNE
    return (unsigned short)r;
}
DEV unsigned pack2(float a, float b) {
    return (unsigned)f2bf(a) | ((unsigned)f2bf(b) << 16);
}
DEV bf16x8 pack8(float4 f0, float4 f1) {
    bf16x8 r;
    r[0] = (short)f2bf(f0.x); r[1] = (short)f2bf(f0.y);
    r[2] = (short)f2bf(f0.z); r[3] = (short)f2bf(f0.w);
    r[4] = (short)f2bf(f1.x); r[5] = (short)f2bf(f1.y);
    r[6] = (short)f2bf(f1.z); r[7] = (short)f2bf(f1.w);
    return r;
}
DEV float sigm(float x) { return 1.f / (1.f + __expf(-x)); }
DEV float tanh_f(float x) {
    float t = __expf(-2.f * fabsf(x));
    float r = (1.f - t) / (1.f + t);
    return copysignf(r, x);
}
// XOR-swizzled LDS byte offset for [row][256 bf16] tiles (512 B rows)
DEV int ldsw(int row, int cb) { return row * 512 + (cb ^ ((row & 7) << 4)); }

// ws layout (bytes); identical footprint to the proven round-3 layout.
// [0, 32768):  u64 ring2[2][2048]  layer-2 recurrent tagged ring
#define OFF_HB0   65536                       // 4 MB u64 Hb0[256][2048]
#define OFF_HB1   (65536 + 4194304)           // 4 MB u64 Hb1[256][2048]
#define OFF_XEA   (65536 + 8388608)           // 2 MB bf16 XeA[256][4096]
#define OFF_HS    (OFF_XEA + 2097152)         // 2 MB bf16 hs[4096][256]
#define OFF_WB    (OFF_HS + 2097152)          // optional 16.4 MB bf16 Wb[32000][256]
#define WB_BYTES  (32000u * 256u * 2u)

// ---------------------------------------------------------------------------
// Embedding gather + fp32->bf16 in per-timestep A-frag order
// ---------------------------------------------------------------------------
__global__ __launch_bounds__(256) void k_embed(const int* __restrict__ x,
                                               const float* __restrict__ emb,
                                               unsigned short* __restrict__ XeA)
{
    int row = blockIdx.x * 8 + (threadIdx.x >> 5);
    int i = threadIdx.x & 31;
    int tok = x[row];
    int b = row >> 8, t = row & 255;
    uint4 v = make_uint4(0, 0, 0, 0);
    if (i < 25) {
        const float* p = emb + (size_t)tok * 200 + i * 8;
        float4 f0 = *(const float4*)p;
        float4 f1 = *(const float4*)(p + 4);
        v.x = pack2(f0.x, f0.y); v.y = pack2(f0.z, f0.w);
        v.z = pack2(f1.x, f1.y); v.w = pack2(f1.z, f1.w);
    }
    int kt = i >> 2, qq = i & 3;
    *(uint4*)(XeA + (size_t)t * 4096 + (size_t)((kt * 64 + qq * 16 + b) * 8)) = v;
}

// ---------------------------------------------------------------------------
// One-shot fcW fp32 -> bf16 pre-conversion (only if workspace allows)
// ---------------------------------------------------------------------------
__global__ __launch_bounds__(256) void k_wcvt(const float* __restrict__ W,
                                              unsigned short* __restrict__ Wb)
{
    size_t i = ((size_t)blockIdx.x * 256 + threadIdx.x) * 8;
    float4 f0 = *(const float4*)(W + i);
    float4 f1 = *(const float4*)(W + i + 4);
    uint4 v;
    v.x = pack2(f0.x, f0.y); v.y = pack2(f0.z, f0.w);
    v.z = pack2(f1.x, f1.y); v.w = pack2(f1.z, f1.w);
    *(uint4*)(Wb + i) = v;
}

// ---------------------------------------------------------------------------
// FC GEMM, B-resident: out[4096,32000] = hs[4096,256] @ fcW^T + bias.
// Grid (250 bn, 4 bm). Each block stages its W-slice (128 cols x K=256,
// bf16, 64 KB XOR-swizzled) in LDS ONCE, then loops 8 M-subtiles of 128
// rows (A-subtile 64 KB/iter). W is read 4x total (131 MB fp32) instead of
// 32x (1.05 GB) -- the round-5 post-mortem showed W re-read traffic through
// L3 was the FC bottleneck, not the logit write. LDS 128 KB, 1 block/CU.
// ---------------------------------------------------------------------------
template <int WB>
__global__ __launch_bounds__(256) void k_fcbig(const unsigned short* __restrict__ X,
                                               const float* __restrict__ W,
                                               const unsigned short* __restrict__ Wb,
                                               const float* __restrict__ bias,
                                               float* __restrict__ outf)
{
    __shared__ __align__(16) char Abuf[65536];
    __shared__ __align__(16) char Bbuf[65536];
    const int tid = threadIdx.x, lane = tid & 63, wave = tid >> 6;
    const int wm = wave >> 1, wn = wave & 1;
    const int bn = blockIdx.x, bm = blockIdx.y;
    const int l15 = lane & 15, q = lane >> 4;

    // stage B once: 128 out-cols x 256 K
#pragma unroll
    for (int it = 0; it < 16; ++it) {
        int p = tid + it * 256;
        int row = p >> 5, c8 = p & 31;
        uint4 bv;
        if (WB) {
            bv = *(const uint4*)(Wb + (size_t)(bn * 128 + row) * 256 + c8 * 8);
        } else {
            const float* wp = W + (size_t)(bn * 128 + row) * 256 + c8 * 8;
            float4 f0 = *(const float4*)wp;
            float4 f1 = *(const float4*)(wp + 4);
            bv.x = pack2(f0.x, f0.y); bv.y = pack2(f0.z, f0.w);
            bv.z = pack2(f1.x, f1.y); bv.w = pack2(f1.z, f1.w);
        }
        *(uint4*)(Bbuf + ldsw(row, c8 * 16)) = bv;
    }

    float bvv[4];
#pragma unroll
    for (int nt = 0; nt < 4; ++nt) bvv[nt] = bias[bn * 128 + wn * 64 + nt * 16 + l15];

    for (int ms = 0; ms < 8; ++ms) {
        __syncthreads();   // B visible (iter 0); Al free from prev compute
#pragma unroll
        for (int it = 0; it < 16; ++it) {
            int p = tid + it * 256;
            int row = p >> 5, c8 = p & 31;
            uint4 av = *(const uint4*)(X + (size_t)(bm * 1024 + ms * 128 + row) * 256 + c8 * 8);
            *(uint4*)(Abuf + ldsw(row, c8 * 16)) = av;
        }
        __syncthreads();   // A visible

        f32x4 acc[4][4];
#pragma unroll
        for (int a = 0; a < 4; a++)
#pragma unroll
            for (int b = 0; b < 4; b++) acc[a][b] = f32x4{0.f, 0.f, 0.f, 0.f};

#pragma unroll
        for (int kt = 0; kt < 8; ++kt) {
            bf16x8 a[4], b[4];
#pragma unroll
            for (int mt = 0; mt < 4; ++mt)
                a[mt] = *(const bf16x8*)(Abuf + ldsw(wm * 64 + mt * 16 + l15, kt * 64 + q * 16));
#pragma unroll
            for (int nt = 0; nt < 4; ++nt)
                b[nt] = *(const bf16x8*)(Bbuf + ldsw(wn * 64 + nt * 16 + l15, kt * 64 + q * 16));
#pragma unroll
            for (int mt = 0; mt < 4; ++mt)
#pragma unroll
                for (int nt = 0; nt < 4; ++nt)
                    acc[mt][nt] = __builtin_amdgcn_mfma_f32_16x16x32_bf16(a[mt], b[nt], acc[mt][nt], 0, 0, 0);
        }

#pragma unroll
        for (int nt = 0; nt < 4; ++nt) {
            int gn = bn * 128 + wn * 64 + nt * 16 + l15;
#pragma unroll
            for (int mt = 0; mt < 4; ++mt) {
#pragma unroll
                for (int r = 0; r < 4; ++r) {
                    int gm = bm * 1024 + ms * 128 + wm * 64 + mt * 16 + q * 4 + r;
                    outf[(size_t)gm * 32000 + gn] = acc[mt][nt][r] + bvv[nt];
                }
            }
        }
    }
}

// ---------------------------------------------------------------------------
// Fused per-row logsumexp + subtract over V=32000 fp32 logits, row in regs.
// (proven in rounds 1-4)
// ---------------------------------------------------------------------------
__global__ __launch_bounds__(1024) void k_lsesub(float* __restrict__ lg)
{
    __shared__ float sm[16], ss[16];
    __shared__ float sL;
    const int row = blockIdx.x, tid = threadIdx.x;
    float* p = lg + (size_t)row * 32000;
    float4 v0[4], v1[4];
    float m = -3.0e38f, s = 0.f;
#pragma unroll
    for (int k = 0; k < 4; ++k) {
        int g = tid + (k << 10);
        if (g < 4000) {
            v0[k] = *(const float4*)(p + g * 8);
            v1[k] = *(const float4*)(p + g * 8 + 4);
            float a0 = fmaxf(fmaxf(v0[k].x, v0[k].y), fmaxf(v0[k].z, v0[k].w));
            float a1 = fmaxf(fmaxf(v1[k].x, v1[k].y), fmaxf(v1[k].z, v1[k].w));
            float ml = fmaxf(a0, a1);
            if (ml > m) { s *= __expf(m - ml); m = ml; }
            s += __expf(v0[k].x - m) + __expf(v0[k].y - m) + __expf(v0[k].z - m) + __expf(v0[k].w - m)
               + __expf(v1[k].x - m) + __expf(v1[k].y - m) + __expf(v1[k].z - m) + __expf(v1[k].w - m);
        }
    }
#pragma unroll
    for (int off = 32; off; off >>= 1) {
        float m2 = __shfl_xor(m, off);
        float s2 = __shfl_xor(s, off);
        float nm = fmaxf(m, m2);
        s = s * __expf(m - nm) + s2 * __expf(m2 - nm);
        m = nm;
    }
    if ((tid & 63) == 0) { sm[tid >> 6] = m; ss[tid >> 6] = s; }
    __syncthreads();
    if (tid == 0) {
        float M = sm[0], S = ss[0];
        for (int w = 1; w < 16; ++w) {
            float m2 = sm[w], s2 = ss[w];
            float nm = fmaxf(M, m2);
            S = S * __expf(M - nm) + s2 * __expf(m2 - nm);
            M = nm;
        }
        sL = M + __logf(S);
    }
    __syncthreads();
    const float L = sL;
#pragma unroll
    for (int k = 0; k < 4; ++k) {
        int g = tid + (k << 10);
        if (g < 4000) {
            v0[k].x -= L; v0[k].y -= L; v0[k].z -= L; v0[k].w -= L;
            v1[k].x -= L; v1[k].y -= L; v1[k].z -= L; v1[k].w -= L;
            *(float4*)(p + g * 8) = v0[k];
            *(float4*)(p + g * 8 + 4) = v1[k];
        }
    }
}

// ---------------------------------------------------------------------------
// Fused 3-layer LSTM scan with cross-layer pipelining (frozen from round 3).
// ---------------------------------------------------------------------------
__global__ __launch_bounds__(256) void k_scan3(
    const float* __restrict__ Wi0, const float* __restrict__ Wh0, const float* __restrict__ b0,
    const float* __restrict__ Wi1, const float* __restrict__ Wh1, const float* __restrict__ b1,
    const float* __restrict__ Wi2, const float* __restrict__ Wh2, const float* __restrict__ b2,
    const unsigned short* __restrict__ XeA,
    unsigned short* __restrict__ hseq,
    unsigned long long* __restrict__ Hb0,
    unsigned long long* __restrict__ Hb1,
    unsigned long long* __restrict__ ring2)
{
    __shared__ __align__(16) unsigned short hX[4096];
    __shared__ __align__(16) unsigned short hH[4096];
    __shared__ float gbuf[64 * 17];
    const int tid = threadIdx.x, lane = tid & 63, wave = tid >> 6;
    const int L = blockIdx.x >> 4, s = blockIdx.x & 15;
    const int l15 = lane & 15, q = lane >> 4;
    const int grow = wave * 256 + s * 16 + l15;

    const float* Wi = (L == 0) ? Wi0 : ((L == 1) ? Wi1 : Wi2);
    const float* Wh = (L == 0) ? Wh0 : ((L == 1) ? Wh1 : Wh2);
    const float* bb = (L == 0) ? b0 : ((L == 1) ? b1 : b2);
    const int KX = (L == 0) ? 200 : 256;

    bf16x8 WiR[8], WhR[8];
#pragma unroll
    for (int kt = 0; kt < 8; ++kt) {
        int k0 = kt * 32 + q * 8;
        {
            const float* p = Wh + (size_t)grow * 256 + k0;
            WhR[kt] = pack8(*(const float4*)p, *(const float4*)(p + 4));
        }
        if (k0 < KX) {
            const float* p = Wi + (size_t)grow * KX + k0;
            WiR[kt] = pack8(*(const float4*)p, *(const float4*)(p + 4));
        } else {
            WiR[kt] = bf16x8{0, 0, 0, 0, 0, 0, 0, 0};
        }
    }
    const float bv = bb[grow];

    const int eb = tid >> 4, eu = tid & 15;
    const bool pub = (eu & 1) == 0;
    int slot;
    {
        int ug = s * 16 + eu;
        int kt = ug >> 5, qq = (ug >> 3) & 3, j = ug & 7;
        slot = ((kt * 64 + qq * 16 + eb) * 8 + j) >> 1;
    }
    float c = 0.f;
    unsigned* hX32 = (unsigned*)hX;
    unsigned* hH32 = (unsigned*)hH;

    const unsigned long long* xbase = (L == 1) ? Hb0 : Hb1;
    unsigned long long* obase = (L == 0) ? Hb0 : Hb1;
    const unsigned long long* rbase = (L == 0) ? Hb0 : Hb1;

    for (int t = 0; t < 256; ++t) {
        if (L == 0) {
            const unsigned* srcx = (const unsigned*)(XeA + (size_t)t * 4096);
            *(uint4*)(hX32 + tid * 8)     = *(const uint4*)(srcx + tid * 8);
            *(uint4*)(hX32 + tid * 8 + 4) = *(const uint4*)(srcx + tid * 8 + 4);
        }
        {
            unsigned long long vx[8], vh[8];
            unsigned pendx = (L > 0) ? 0xffu : 0u;
            unsigned pendh = (t > 0) ? 0xffu : 0u;
            const unsigned long long* sx = xbase + (size_t)t * 2048 + tid;
            const unsigned long long* sh =
                (L == 2) ? (ring2 + ((t - 1) & 1) * 2048 + tid)
                         : (rbase + (size_t)((t > 0) ? (t - 1) : 0) * 2048 + tid);
            const unsigned ex = (unsigned)(t + 1), eh = (unsigned)t;
            while (pendx | pendh) {
#pragma unroll
                for (int i = 0; i < 8; ++i)
                    if (pendx & (1u << i))
                        vx[i] = __hip_atomic_load(sx + i * 256, __ATOMIC_RELAXED,
                                                  __HIP_MEMORY_SCOPE_AGENT);
#pragma unroll
                for (int i = 0; i < 8; ++i)
                    if (pendh & (1u << i))
                        vh[i] = __hip_atomic_load(sh + i * 256, __ATOMIC_RELAXED,
                                                  __HIP_MEMORY_SCOPE_AGENT);
#pragma unroll
                for (int i = 0; i < 8; ++i) {
                    if ((pendx & (1u << i)) && (unsigned)(vx[i] >> 32) == ex) pendx &= ~(1u << i);
                    if ((pendh & (1u << i)) && (unsigned)(vh[i] >> 32) == eh) pendh &= ~(1u << i);
                }
                if (pendx | pendh) __builtin_amdgcn_s_sleep(1);
            }
            if (L > 0) {
#pragma unroll
                for (int i = 0; i < 8; ++i) hX32[tid + i * 256] = (unsigned)vx[i];
            }
            if (t > 0) {
#pragma unroll
                for (int i = 0; i < 8; ++i) hH32[tid + i * 256] = (unsigned)vh[i];
            } else {
#pragma unroll
                for (int i = 0; i < 8; ++i) hH32[tid + i * 256] = 0u;
            }
        }
        __syncthreads();

        f32x4 acc0 = {bv, bv, bv, bv};
        f32x4 acc1 = {0.f, 0.f, 0.f, 0.f};
#pragma unroll
        for (int kt = 0; kt < 8; ++kt) {
            bf16x8 ax = *(const bf16x8*)(hX + (kt * 64 + lane) * 8);
            acc0 = __builtin_amdgcn_mfma_f32_16x16x32_bf16(ax, WiR[kt], acc0, 0, 0, 0);
            bf16x8 ah = *(const bf16x8*)(hH + (kt * 64 + lane) * 8);
            acc1 = __builtin_amdgcn_mfma_f32_16x16x32_bf16(ah, WhR[kt], acc1, 0, 0, 0);
        }
        {
            int rowb = wave * 16 + l15;
#pragma unroll
            for (int r = 0; r < 4; ++r) gbuf[rowb * 17 + q * 4 + r] = acc0[r] + acc1[r];
        }
        __syncthreads();

        float gi = gbuf[(0 * 16 + eu) * 17 + eb];
        float gf = gbuf[(1 * 16 + eu) * 17 + eb];
        float gg = gbuf[(2 * 16 + eu) * 17 + eb];
        float go = gbuf[(3 * 16 + eu) * 17 + eb];
        float i_ = sigm(gi), f_ = sigm(gf), g_ = tanh_f(gg), o_ = sigm(go);
        c = f_ * c + i_ * g_;
        float h = o_ * tanh_f(c);
        float hn = __shfl_xor(h, 1);
        if (pub) {
            unsigned pk = pack2(h, hn);
            unsigned long long val =
                ((unsigned long long)(unsigned)(t + 1) << 32) | (unsigned long long)pk;
            if (L == 2) {
                __hip_atomic_store(ring2 + (t & 1) * 2048 + slot, val, __ATOMIC_RELAXED,
                                   __HIP_MEMORY_SCOPE_AGENT);
                *(unsigned*)(hseq + (size_t)(eb * 256 + t) * 256 + s * 16 + eu) = pk;
            } else {
                __hip_atomic_store(obase + (size_t)t * 2048 + slot, val, __ATOMIC_RELAXED,
                                   __HIP_MEMORY_SCOPE_AGENT);
            }
        }
    }
}

// ---------------------------------------------------------------------------
extern "C" void kernel_launch(void* const* d_in, const int* in_sizes, int n_in,
                              void* d_out, int out_size, void* d_ws, size_t ws_size,
                              hipStream_t stream)
{
    const int* x = (const int*)d_in[0];
    const float* emb = (const float*)d_in[1];
    const float* Wi0 = (const float*)d_in[2];
    const float* Wh0 = (const float*)d_in[3];
    const float* b0  = (const float*)d_in[4];
    const float* Wi1 = (const float*)d_in[5];
    const float* Wh1 = (const float*)d_in[6];
    const float* b1  = (const float*)d_in[7];
    const float* Wi2 = (const float*)d_in[8];
    const float* Wh2 = (const float*)d_in[9];
    const float* b2  = (const float*)d_in[10];
    const float* fcW = (const float*)d_in[11];
    const float* fcb = (const float*)d_in[12];
    float* out = (float*)d_out;

    uint8_t* w = (uint8_t*)d_ws;
    unsigned long long* ring2 = (unsigned long long*)w;
    unsigned long long* Hb0 = (unsigned long long*)(w + OFF_HB0);
    unsigned long long* Hb1 = (unsigned long long*)(w + OFF_HB1);
    unsigned short* XeA = (unsigned short*)(w + OFF_XEA);
    unsigned short* hs  = (unsigned short*)(w + OFF_HS);
    unsigned short* Wb  = (unsigned short*)(w + OFF_WB);
    const bool wb_ok = ws_size >= (size_t)OFF_WB + (size_t)WB_BYTES;

    hipMemsetAsync(w, 0, OFF_XEA, stream);   // ring2 + Hb0/Hb1 tags

    if (wb_ok) k_wcvt<<<4000, 256, 0, stream>>>(fcW, Wb);

    k_embed<<<512, 256, 0, stream>>>(x, emb, XeA);

    k_scan3<<<48, 256, 0, stream>>>(Wi0, Wh0, b0, Wi1, Wh1, b1, Wi2, Wh2, b2,
                                    XeA, hs, Hb0, Hb1, ring2);

    if (wb_ok)
        k_fcbig<1><<<dim3(250, 4), 256, 0, stream>>>(hs, nullptr, Wb, fcb, out);
    else
        k_fcbig<0><<<dim3(250, 4), 256, 0, stream>>>(hs, fcW, nullptr, fcb, out);

    k_lsesub<<<4096, 1024, 0, stream>>>(out);
}